// Round 10
// baseline (52.566 us; speedup 1.0000x reference)
//
#include <hip/hip_runtime.h>
#include <math.h>

namespace {

constexpr int D = 256;
constexpr int H = 8;

typedef __attribute__((ext_vector_type(8))) short bf16x8;
typedef __attribute__((ext_vector_type(4))) float f32x4;

__device__ inline unsigned short bf16rn(float x) {
  unsigned u = __builtin_bit_cast(unsigned, x);
  u += 0x7fffu + ((u >> 16) & 1u);
  return (unsigned short)(u >> 16);
}
__device__ inline float bf16tof(unsigned short b) {
  return __builtin_bit_cast(float, (unsigned)b << 16);
}

// Async global->LDS, 16B per lane: LDS dest = wave-uniform base + lane*16.
__device__ inline void async_copy16(float4* lds_dst, const float4* gsrc) {
  __builtin_amdgcn_global_load_lds(
      (const __attribute__((address_space(1))) unsigned int*)(gsrc),
      (__attribute__((address_space(3))) unsigned int*)(lds_dst), 16, 0, 0);
}

// ---------------- Kernel 1: qW[bn,h,e] = sum_d q[bn,d] * W[h,d,e] ----------------
// grid (64, 8, 2) = (bn-tile, h, e-half): 1024 blocks -> 4 blocks/CU (4 waves/SIMD).
// Per block: 16 bn x 128 e, K = 256. W streamed in 16-row chunks (8 KB) via
// global_load_lds, double-buffered; group g = tid>>5 owns bn rows {2g, 2g+1},
// lane-in-group owns one e-quad. Inner loop: 1 b64 broadcast + 1 b128 + 8 FMA.
__global__ __launch_bounds__(256) void qw_kernel(
    const float* __restrict__ q, const float* __restrict__ W,
    float* __restrict__ qW) {
  __shared__ float qT[256][22];       // [d][bn-row]; stride 88B: 8B-aligned, 2-way banks
  __shared__ float Wc[2][16][128];    // 2 x 8 KB W chunks (gload_lds dest: linear rows)
  const int tid = threadIdx.x;
  const int bn0 = blockIdx.x * 16;
  const int h   = blockIdx.y;
  const int eh  = blockIdx.z;         // e-half: cols eh*128 .. eh*128+127
  const int wid = tid >> 6;
  const int ln  = tid & 63;

  // W[h] as float4, offset to this e-half; row d = Wh4 + d*64, 32 quads wide.
  const float4* Wh4 = reinterpret_cast<const float4*>(W) + (size_t)h * 16384 + eh * 32;

  // prologue: issue W chunk 0 (wave wid -> rows wid*4..wid*4+3, 2 rows per instr:
  // lanes 0-31 row p*2, lanes 32-63 row p*2+1; LDS rows contiguous at 512 B).
  #pragma unroll
  for (int p = 0; p < 2; ++p) {
    const int row = wid * 4 + p * 2;
    async_copy16(reinterpret_cast<float4*>(&Wc[0][row][0]),
                 Wh4 + (size_t)(row + (ln >> 5)) * 64 + (ln & 31));
  }
  // stage qT (overlaps the async W copies)
  for (int i = 0; i < 16; ++i)
    qT[tid][i] = q[(size_t)(bn0 + i) * D + tid];
  __syncthreads();   // drains W chunk 0 (vmcnt) + qT writes (lgkm)

  const int g  = tid >> 5;            // bn-row pair {2g, 2g+1}
  const int eq = tid & 31;            // e-quad within half
  float4 accA = make_float4(0.f, 0.f, 0.f, 0.f);
  float4 accB = make_float4(0.f, 0.f, 0.f, 0.f);

  int buf = 0;
  for (int c = 0; c < 16; ++c) {
    if (c < 15) {
      #pragma unroll
      for (int p = 0; p < 2; ++p) {
        const int row = wid * 4 + p * 2;
        async_copy16(reinterpret_cast<float4*>(&Wc[buf ^ 1][row][0]),
                     Wh4 + (size_t)((c + 1) * 16 + row + (ln >> 5)) * 64 + (ln & 31));
      }
    }
    __builtin_amdgcn_sched_barrier(0);

    #pragma unroll
    for (int dl = 0; dl < 16; ++dl) {
      const int d = c * 16 + dl;
      float2 qv = *reinterpret_cast<const float2*>(&qT[d][g * 2]);   // 2-addr broadcast
      float4 wv = *reinterpret_cast<const float4*>(&Wc[buf][dl][eq << 2]);
      accA.x += qv.x * wv.x; accA.y += qv.x * wv.y;
      accA.z += qv.x * wv.z; accA.w += qv.x * wv.w;
      accB.x += qv.y * wv.x; accB.y += qv.y * wv.y;
      accB.z += qv.y * wv.z; accB.w += qv.y * wv.w;
    }
    __syncthreads();   // compute reads of buf done; prefetch into buf^1 drained
    buf ^= 1;
  }

  const size_t ecol = (size_t)h * 256 + eh * 128 + (eq << 2);
  *reinterpret_cast<float4*>(&qW[(size_t)(bn0 + 2 * g) * 2048 + ecol])     = accA;
  *reinterpret_cast<float4*>(&qW[(size_t)(bn0 + 2 * g + 1) * 2048 + ecol]) = accB;
}

// ---------------- Kernel 2: scores via split-bf16 MFMA + chunk-softmax ----------------
// (byte-identical to R8/R9 — verified)
constexpr int FA_HI = 0;
constexpr int FA_LO = 16640;   // 2 tiles * 8 ks * 1040
constexpr int FB_HI = 33280;
constexpr int FB_LO = 41600;   // + 8*1040
constexpr int SMEM_BYTES = 49920;

__global__ __launch_bounds__(256) void score_kernel(
    const float* __restrict__ qW, const float* __restrict__ kin,
    const float* __restrict__ bin, float* __restrict__ attn_out) {
  __shared__ alignas(16) long long smem_ll[SMEM_BYTES / 8];
  char* sm = reinterpret_cast<char*>(smem_ll);
  const int tid = threadIdx.x;
  const int bn  = blockIdx.x;
  const int kh  = blockIdx.y;
  const int wid = tid >> 6;
  const int ln  = tid & 63;

  // ---- stage: issue all global loads first (10 independent, coalesced)
  const float4* k4 = reinterpret_cast<const float4*>(kin) +
                     (size_t)bn * 4096 + (size_t)kh * 2048;
  float4 kv[8];
  #pragma unroll
  for (int i = 0; i < 8; ++i) kv[i] = k4[tid + 256 * i];
  const float4* qw4 = reinterpret_cast<const float4*>(qW) + (size_t)bn * 512;
  float4 qv0 = qw4[tid];
  float4 qv1 = qw4[tid + 256];

  // ---- zero-fill unwritten B slots (cols 8-15)
  {
    const uint4 z = make_uint4(0u, 0u, 0u, 0u);
    #pragma unroll
    for (int i = 0; i < 2; ++i) {
      int idx = tid + 256 * i;
      int region = idx >> 8;
      int rem = idx & 255;
      int ks = rem >> 5, slot = 32 + (rem & 31);
      int off = (region ? FB_LO : FB_HI) + ks * 1040 + slot * 16;
      *reinterpret_cast<uint4*>(sm + off) = z;
    }
  }

  // ---- convert + fragment-order LDS writes
  #pragma unroll
  for (int i = 0; i < 8; ++i) {
    int quad = tid + 256 * i;
    int row = quad >> 6, equad = quad & 63;
    int tile = row >> 4, lrow = row & 15;
    int ks = equad >> 3, g = (equad >> 1) & 3, j0 = (equad & 1) * 4;
    int base = tile * 8320 + ks * 1040 + (lrow * 4 + g) * 16 + j0 * 2;
    float e[4] = {kv[i].x, kv[i].y, kv[i].z, kv[i].w};
    unsigned short h0 = bf16rn(e[0]), h1 = bf16rn(e[1]),
                   h2 = bf16rn(e[2]), h3 = bf16rn(e[3]);
    unsigned short l0 = bf16rn(e[0] - bf16tof(h0)), l1 = bf16rn(e[1] - bf16tof(h1)),
                   l2 = bf16rn(e[2] - bf16tof(h2)), l3 = bf16rn(e[3] - bf16tof(h3));
    uint2 hw = make_uint2((unsigned)h0 | ((unsigned)h1 << 16),
                          (unsigned)h2 | ((unsigned)h3 << 16));
    uint2 lw = make_uint2((unsigned)l0 | ((unsigned)l1 << 16),
                          (unsigned)l2 | ((unsigned)l3 << 16));
    *reinterpret_cast<uint2*>(sm + FA_HI + base) = hw;
    *reinterpret_cast<uint2*>(sm + FA_LO + base) = lw;
  }
  #pragma unroll
  for (int i = 0; i < 2; ++i) {
    int p = tid + 256 * i;
    int hh = p >> 6, equad = p & 63;
    int ks = equad >> 3, g = (equad >> 1) & 3, j0 = (equad & 1) * 4;
    int base = ks * 1040 + (hh * 4 + g) * 16 + j0 * 2;
    float4 qv = i == 0 ? qv0 : qv1;
    float e[4] = {qv.x, qv.y, qv.z, qv.w};
    unsigned short h0 = bf16rn(e[0]), h1 = bf16rn(e[1]),
                   h2 = bf16rn(e[2]), h3 = bf16rn(e[3]);
    unsigned short l0 = bf16rn(e[0] - bf16tof(h0)), l1 = bf16rn(e[1] - bf16tof(h1)),
                   l2 = bf16rn(e[2] - bf16tof(h2)), l3 = bf16rn(e[3] - bf16tof(h3));
    uint2 hw = make_uint2((unsigned)h0 | ((unsigned)h1 << 16),
                          (unsigned)h2 | ((unsigned)h3 << 16));
    uint2 lw = make_uint2((unsigned)l0 | ((unsigned)l1 << 16),
                          (unsigned)l2 | ((unsigned)l3 << 16));
    *reinterpret_cast<uint2*>(sm + FB_HI + base) = hw;
    *reinterpret_cast<uint2*>(sm + FB_LO + base) = lw;
  }
  __syncthreads();
  if (wid >= 2) return;

  // ---- MFMA: wave = tile (16 k-rows), full K=256
  const int T = wid;
  const int slot_r = (ln & 15) * 4 + (ln >> 4);
  const char* paH = sm + FA_HI + T * 8320 + slot_r * 16;
  const char* paL = sm + FA_LO + T * 8320 + slot_r * 16;
  const char* pbH = sm + FB_HI + slot_r * 16;
  const char* pbL = sm + FB_LO + slot_r * 16;
  f32x4 acc = {0.f, 0.f, 0.f, 0.f};
  #pragma unroll
  for (int ks = 0; ks < 8; ++ks) {
    bf16x8 aH = *reinterpret_cast<const bf16x8*>(paH + ks * 1040);
    bf16x8 aL = *reinterpret_cast<const bf16x8*>(paL + ks * 1040);
    bf16x8 bH = *reinterpret_cast<const bf16x8*>(pbH + ks * 1040);
    bf16x8 bL = *reinterpret_cast<const bf16x8*>(pbL + ks * 1040);
    acc = __builtin_amdgcn_mfma_f32_16x16x32_bf16(aH, bH, acc, 0, 0, 0);
    acc = __builtin_amdgcn_mfma_f32_16x16x32_bf16(aH, bL, acc, 0, 0, 0);
    acc = __builtin_amdgcn_mfma_f32_16x16x32_bf16(aL, bH, acc, 0, 0, 0);
  }

  // ---- softmax on C-frags
  const int col = ln & 15;
  const bool valid = col < 8;
  const float bias = bin[ln & 7];
  float x0 = acc[0] + bias, x1 = acc[1] + bias, x2 = acc[2] + bias, x3 = acc[3] + bias;
  float m = valid ? fmaxf(fmaxf(x0, x1), fmaxf(x2, x3)) : -1e30f;
  m = fmaxf(m, __shfl_xor(m, 1, 64));
  m = fmaxf(m, __shfl_xor(m, 2, 64));
  m = fmaxf(m, __shfl_xor(m, 4, 64));
  m = fmaxf(m, __shfl_xor(m, 16, 64));
  float e0 = valid ? expf(x0 - m) : 0.f;
  float e1 = valid ? expf(x1 - m) : 0.f;
  float e2 = valid ? expf(x2 - m) : 0.f;
  float e3 = valid ? expf(x3 - m) : 0.f;
  float s = e0 + e1 + e2 + e3;
  s += __shfl_xor(s, 1, 64);
  s += __shfl_xor(s, 2, 64);
  s += __shfl_xor(s, 4, 64);
  s += __shfl_xor(s, 16, 64);
  if (valid) {
    float inv = 1.f / s;
    size_t base = (size_t)bn * 512 + (size_t)(kh * 32 + T * 16 + (ln >> 4) * 4) * 8 + col;
    attn_out[base]      = e0 * inv;
    attn_out[base + 8]  = e1 * inv;
    attn_out[base + 16] = e2 * inv;
    attn_out[base + 24] = e3 * inv;
  }
}

// ---------------- Kernel 3: PV ----------------
// (byte-identical to R8/R9 — verified)
__global__ __launch_bounds__(256) void pv_kernel(
    const float* __restrict__ vin, const float* __restrict__ attn_in,
    float* __restrict__ out) {
  __shared__ float wpart[4][64];
  __shared__ float wsum[64];
  __shared__ float s_red[4][260];
  const int tid = threadIdx.x;
  const int bn  = blockIdx.x;
  const int wid = tid >> 6;
  const int ln  = tid & 63;

  float a0 = attn_in[(size_t)bn * 512 + tid];
  float a1 = attn_in[(size_t)bn * 512 + 256 + tid];
  wpart[wid][ln] = a0 + a1;
  __syncthreads();
  if (tid < 64) wsum[tid] = wpart[0][tid] + wpart[1][tid] + wpart[2][tid] + wpart[3][tid];
  __syncthreads();

  const float4* v4 = reinterpret_cast<const float4*>(vin) + (size_t)bn * 4096;
  float4 acc = make_float4(0.f, 0.f, 0.f, 0.f);
  #pragma unroll 8
  for (int i = 0; i < 16; ++i) {
    const int r = wid + 4 * i;
    float w = wsum[r];
    float4 vv = v4[r * 64 + ln];
    acc.x += w * vv.x; acc.y += w * vv.y; acc.z += w * vv.z; acc.w += w * vv.w;
  }
  *reinterpret_cast<float4*>(&s_red[wid][ln << 2]) = acc;
  __syncthreads();

  out[(size_t)bn * D + tid] =
      s_red[0][tid] + s_red[1][tid] + s_red[2][tid] + s_red[3][tid];
}

}  // namespace

extern "C" void kernel_launch(void* const* d_in, const int* in_sizes, int n_in,
                              void* d_out, int out_size, void* d_ws, size_t ws_size,
                              hipStream_t stream) {
  const float* q = (const float*)d_in[0];   // (8,128,1,256)
  const float* k = (const float*)d_in[1];   // (8,128,64,256)
  const float* v = (const float*)d_in[2];   // (8,128,64,256)
  const float* W = (const float*)d_in[3];   // (8,256,256)
  const float* b = (const float*)d_in[4];   // (8,)

  float* out  = (float*)d_out;              // output: 262144 f32
  float* attn = out + 262144;               // attn:   524288 f32
  float* qWbuf = (float*)d_ws;              // 1024*2048 f32 = 8 MiB scratch

  hipLaunchKernelGGL(qw_kernel, dim3(64, 8, 2), dim3(256), 0, stream, q, W, qWbuf);
  hipLaunchKernelGGL(score_kernel, dim3(1024, 2), dim3(256), 0, stream,
                     qWbuf, k, b, attn);
  hipLaunchKernelGGL(pv_kernel, dim3(1024), dim3(256), 0, stream,
                     v, attn, out);
}

// Round 11
// 47.466 us; speedup vs baseline: 1.1074x; 1.1074x over previous
//
#include <hip/hip_runtime.h>
#include <math.h>

namespace {

constexpr int D = 256;
constexpr int H = 8;

typedef __attribute__((ext_vector_type(8))) short bf16x8;
typedef __attribute__((ext_vector_type(4))) float f32x4;

__device__ inline unsigned short bf16rn(float x) {
  unsigned u = __builtin_bit_cast(unsigned, x);
  u += 0x7fffu + ((u >> 16) & 1u);
  return (unsigned short)(u >> 16);
}
__device__ inline float bf16tof(unsigned short b) {
  return __builtin_bit_cast(float, (unsigned)b << 16);
}

// workspace byte offsets
constexpr size_t OFF_QW  = 0;                          // 8 MiB f32 qW
constexpr size_t OFF_WFH = (size_t)8 << 20;            // 1 MiB W-frag hi
constexpr size_t OFF_WFL = (size_t)9 << 20;            // 1 MiB W-frag lo
constexpr size_t OFF_QFH = (size_t)10 << 20;           // 512 KiB q-frag hi
constexpr size_t OFF_QFL = ((size_t)10 << 20) + ((size_t)512 << 10);

// ---------------- Kernel 0: prep — bf16 hi/lo fragments of q and W ----------------
// Fragment unit = 16B (8 bf16 along d). Index gid: W part (gid<65536):
// [he=128][ks=8][lane=64]; element j -> W[h][ks*32+(l>>4)*8+j][et*16+(l&15)],
// h=he>>4, et=he&15. q part: [bt=64][ks=8][lane=64]; q[bt*16+(l&15)][ks*32+(l>>4)*8+j].
// Same k-placement for A and B -> any HW k-permutation cancels (R8-verified trick).
__global__ __launch_bounds__(256) void prep_kernel(
    const float* __restrict__ q, const float* __restrict__ W,
    char* __restrict__ ws) {
  const int gid = blockIdx.x * 256 + threadIdx.x;
  float e[8];
  char *hi_base, *lo_base;
  size_t outoff;
  if (gid < 65536) {          // blocks 0..255: W part (uniform per block)
    const int l = gid & 63, ks = (gid >> 6) & 7, he = gid >> 9;
    const int h = he >> 4, et = he & 15;
    const int d0 = ks * 32 + ((l >> 4) << 3);
    const int ecol = et * 16 + (l & 15);
    const float* src = W + (size_t)h * 65536 + (size_t)d0 * 256 + ecol;
    #pragma unroll
    for (int j = 0; j < 8; ++j) e[j] = src[j * 256];
    hi_base = ws + OFF_WFH; lo_base = ws + OFF_WFL;
    outoff = (size_t)gid * 16;
  } else {                    // blocks 256..383: q part
    const int t = gid - 65536;
    const int l = t & 63, ks = (t >> 6) & 7, bt = t >> 9;
    const int row = bt * 16 + (l & 15);
    const int d0 = ks * 32 + ((l >> 4) << 3);
    const float4* src = reinterpret_cast<const float4*>(q + (size_t)row * 256 + d0);
    float4 a = src[0], b = src[1];
    e[0] = a.x; e[1] = a.y; e[2] = a.z; e[3] = a.w;
    e[4] = b.x; e[5] = b.y; e[6] = b.z; e[7] = b.w;
    hi_base = ws + OFF_QFH; lo_base = ws + OFF_QFL;
    outoff = (size_t)t * 16;
  }
  unsigned hw[4], lw[4];
  #pragma unroll
  for (int p = 0; p < 4; ++p) {
    unsigned short h0 = bf16rn(e[2 * p]), h1 = bf16rn(e[2 * p + 1]);
    unsigned short l0 = bf16rn(e[2 * p] - bf16tof(h0));
    unsigned short l1 = bf16rn(e[2 * p + 1] - bf16tof(h1));
    hw[p] = (unsigned)h0 | ((unsigned)h1 << 16);
    lw[p] = (unsigned)l0 | ((unsigned)l1 << 16);
  }
  *reinterpret_cast<uint4*>(hi_base + outoff) = make_uint4(hw[0], hw[1], hw[2], hw[3]);
  *reinterpret_cast<uint4*>(lo_base + outoff) = make_uint4(lw[0], lw[1], lw[2], lw[3]);
}

// ---------------- Kernel 1: qW via split-bf16 MFMA ----------------
// 256 blocks x 256 thr, no LDS/barriers. Wave w: bng = w>>5 (2 bn-tiles),
// heg = w&31 (4 (h,e)-tiles). Frag loads are lane-ordered -> 1KB coalesced
// global_load_dwordx4. 8 ksteps x (2x4 tiles x 3 MFMA). C layout (R8-verified):
// col = l&15 (B/e-dim), row = (l>>4)*4+r (A/bn-dim); qW col index = he*16 + col.
__global__ __launch_bounds__(256) void qw_mfma_kernel(
    const char* __restrict__ ws_in, float* __restrict__ qW) {
  const int tid = threadIdx.x;
  const int w   = blockIdx.x * 4 + (tid >> 6);
  const int l   = tid & 63;
  const int bng = w >> 5;    // 0..31
  const int heg = w & 31;    // 0..31
  const char* qfh = ws_in + OFF_QFH;
  const char* qfl = ws_in + OFF_QFL;
  const char* wfh = ws_in + OFF_WFH;
  const char* wfl = ws_in + OFF_WFL;

  f32x4 acc[2][4];
  #pragma unroll
  for (int i = 0; i < 2; ++i)
    #pragma unroll
    for (int j = 0; j < 4; ++j) acc[i][j] = {0.f, 0.f, 0.f, 0.f};

  #pragma unroll 2
  for (int ks = 0; ks < 8; ++ks) {
    bf16x8 aH[2], aL[2], bH[4], bL[4];
    #pragma unroll
    for (int i = 0; i < 2; ++i) {
      const size_t off = ((size_t)((bng * 2 + i) * 8 + ks) * 64 + l) * 16;
      aH[i] = *reinterpret_cast<const bf16x8*>(qfh + off);
      aL[i] = *reinterpret_cast<const bf16x8*>(qfl + off);
    }
    #pragma unroll
    for (int j = 0; j < 4; ++j) {
      const size_t off = ((size_t)((heg * 4 + j) * 8 + ks) * 64 + l) * 16;
      bH[j] = *reinterpret_cast<const bf16x8*>(wfh + off);
      bL[j] = *reinterpret_cast<const bf16x8*>(wfl + off);
    }
    #pragma unroll
    for (int i = 0; i < 2; ++i)
      #pragma unroll
      for (int j = 0; j < 4; ++j) {
        acc[i][j] = __builtin_amdgcn_mfma_f32_16x16x32_bf16(aH[i], bH[j], acc[i][j], 0, 0, 0);
        acc[i][j] = __builtin_amdgcn_mfma_f32_16x16x32_bf16(aH[i], bL[j], acc[i][j], 0, 0, 0);
        acc[i][j] = __builtin_amdgcn_mfma_f32_16x16x32_bf16(aL[i], bH[j], acc[i][j], 0, 0, 0);
      }
  }

  const int rbase = (l >> 4) * 4;
  const int col   = l & 15;
  #pragma unroll
  for (int i = 0; i < 2; ++i)
    #pragma unroll
    for (int j = 0; j < 4; ++j) {
      const size_t cidx = (size_t)(heg * 4 + j) * 16 + col;
      #pragma unroll
      for (int r = 0; r < 4; ++r) {
        const int bn = (bng * 2 + i) * 16 + rbase + r;
        qW[(size_t)bn * 2048 + cidx] = acc[i][j][r];
      }
    }
}

// ---------------- Kernel 2: scores via split-bf16 MFMA + chunk-softmax ----------------
// (byte-identical to R8/R9/R10 — verified)
constexpr int FA_HI = 0;
constexpr int FA_LO = 16640;   // 2 tiles * 8 ks * 1040
constexpr int FB_HI = 33280;
constexpr int FB_LO = 41600;   // + 8*1040
constexpr int SMEM_BYTES = 49920;

__global__ __launch_bounds__(256) void score_kernel(
    const float* __restrict__ qW, const float* __restrict__ kin,
    const float* __restrict__ bin, float* __restrict__ attn_out) {
  __shared__ alignas(16) long long smem_ll[SMEM_BYTES / 8];
  char* sm = reinterpret_cast<char*>(smem_ll);
  const int tid = threadIdx.x;
  const int bn  = blockIdx.x;
  const int kh  = blockIdx.y;
  const int wid = tid >> 6;
  const int ln  = tid & 63;

  // ---- stage: issue all global loads first (10 independent, coalesced)
  const float4* k4 = reinterpret_cast<const float4*>(kin) +
                     (size_t)bn * 4096 + (size_t)kh * 2048;
  float4 kv[8];
  #pragma unroll
  for (int i = 0; i < 8; ++i) kv[i] = k4[tid + 256 * i];
  const float4* qw4 = reinterpret_cast<const float4*>(qW) + (size_t)bn * 512;
  float4 qv0 = qw4[tid];
  float4 qv1 = qw4[tid + 256];

  // ---- zero-fill unwritten B slots (cols 8-15)
  {
    const uint4 z = make_uint4(0u, 0u, 0u, 0u);
    #pragma unroll
    for (int i = 0; i < 2; ++i) {
      int idx = tid + 256 * i;
      int region = idx >> 8;
      int rem = idx & 255;
      int ks = rem >> 5, slot = 32 + (rem & 31);
      int off = (region ? FB_LO : FB_HI) + ks * 1040 + slot * 16;
      *reinterpret_cast<uint4*>(sm + off) = z;
    }
  }

  // ---- convert + fragment-order LDS writes
  #pragma unroll
  for (int i = 0; i < 8; ++i) {
    int quad = tid + 256 * i;
    int row = quad >> 6, equad = quad & 63;
    int tile = row >> 4, lrow = row & 15;
    int ks = equad >> 3, g = (equad >> 1) & 3, j0 = (equad & 1) * 4;
    int base = tile * 8320 + ks * 1040 + (lrow * 4 + g) * 16 + j0 * 2;
    float e[4] = {kv[i].x, kv[i].y, kv[i].z, kv[i].w};
    unsigned short h0 = bf16rn(e[0]), h1 = bf16rn(e[1]),
                   h2 = bf16rn(e[2]), h3 = bf16rn(e[3]);
    unsigned short l0 = bf16rn(e[0] - bf16tof(h0)), l1 = bf16rn(e[1] - bf16tof(h1)),
                   l2 = bf16rn(e[2] - bf16tof(h2)), l3 = bf16rn(e[3] - bf16tof(h3));
    uint2 hw = make_uint2((unsigned)h0 | ((unsigned)h1 << 16),
                          (unsigned)h2 | ((unsigned)h3 << 16));
    uint2 lw = make_uint2((unsigned)l0 | ((unsigned)l1 << 16),
                          (unsigned)l2 | ((unsigned)l3 << 16));
    *reinterpret_cast<uint2*>(sm + FA_HI + base) = hw;
    *reinterpret_cast<uint2*>(sm + FA_LO + base) = lw;
  }
  #pragma unroll
  for (int i = 0; i < 2; ++i) {
    int p = tid + 256 * i;
    int hh = p >> 6, equad = p & 63;
    int ks = equad >> 3, g = (equad >> 1) & 3, j0 = (equad & 1) * 4;
    int base = ks * 1040 + (hh * 4 + g) * 16 + j0 * 2;
    float4 qv = i == 0 ? qv0 : qv1;
    float e[4] = {qv.x, qv.y, qv.z, qv.w};
    unsigned short h0 = bf16rn(e[0]), h1 = bf16rn(e[1]),
                   h2 = bf16rn(e[2]), h3 = bf16rn(e[3]);
    unsigned short l0 = bf16rn(e[0] - bf16tof(h0)), l1 = bf16rn(e[1] - bf16tof(h1)),
                   l2 = bf16rn(e[2] - bf16tof(h2)), l3 = bf16rn(e[3] - bf16tof(h3));
    uint2 hw = make_uint2((unsigned)h0 | ((unsigned)h1 << 16),
                          (unsigned)h2 | ((unsigned)h3 << 16));
    uint2 lw = make_uint2((unsigned)l0 | ((unsigned)l1 << 16),
                          (unsigned)l2 | ((unsigned)l3 << 16));
    *reinterpret_cast<uint2*>(sm + FB_HI + base) = hw;
    *reinterpret_cast<uint2*>(sm + FB_LO + base) = lw;
  }
  __syncthreads();
  if (wid >= 2) return;

  // ---- MFMA: wave = tile (16 k-rows), full K=256
  const int T = wid;
  const int slot_r = (ln & 15) * 4 + (ln >> 4);
  const char* paH = sm + FA_HI + T * 8320 + slot_r * 16;
  const char* paL = sm + FA_LO + T * 8320 + slot_r * 16;
  const char* pbH = sm + FB_HI + slot_r * 16;
  const char* pbL = sm + FB_LO + slot_r * 16;
  f32x4 acc = {0.f, 0.f, 0.f, 0.f};
  #pragma unroll
  for (int ks = 0; ks < 8; ++ks) {
    bf16x8 aH = *reinterpret_cast<const bf16x8*>(paH + ks * 1040);
    bf16x8 aL = *reinterpret_cast<const bf16x8*>(paL + ks * 1040);
    bf16x8 bH = *reinterpret_cast<const bf16x8*>(pbH + ks * 1040);
    bf16x8 bL = *reinterpret_cast<const bf16x8*>(pbL + ks * 1040);
    acc = __builtin_amdgcn_mfma_f32_16x16x32_bf16(aH, bH, acc, 0, 0, 0);
    acc = __builtin_amdgcn_mfma_f32_16x16x32_bf16(aH, bL, acc, 0, 0, 0);
    acc = __builtin_amdgcn_mfma_f32_16x16x32_bf16(aL, bH, acc, 0, 0, 0);
  }

  // ---- softmax on C-frags
  const int col = ln & 15;
  const bool valid = col < 8;
  const float bias = bin[ln & 7];
  float x0 = acc[0] + bias, x1 = acc[1] + bias, x2 = acc[2] + bias, x3 = acc[3] + bias;
  float m = valid ? fmaxf(fmaxf(x0, x1), fmaxf(x2, x3)) : -1e30f;
  m = fmaxf(m, __shfl_xor(m, 1, 64));
  m = fmaxf(m, __shfl_xor(m, 2, 64));
  m = fmaxf(m, __shfl_xor(m, 4, 64));
  m = fmaxf(m, __shfl_xor(m, 16, 64));
  float e0 = valid ? expf(x0 - m) : 0.f;
  float e1 = valid ? expf(x1 - m) : 0.f;
  float e2 = valid ? expf(x2 - m) : 0.f;
  float e3 = valid ? expf(x3 - m) : 0.f;
  float s = e0 + e1 + e2 + e3;
  s += __shfl_xor(s, 1, 64);
  s += __shfl_xor(s, 2, 64);
  s += __shfl_xor(s, 4, 64);
  s += __shfl_xor(s, 16, 64);
  if (valid) {
    float inv = 1.f / s;
    size_t base = (size_t)bn * 512 + (size_t)(kh * 32 + T * 16 + (ln >> 4) * 4) * 8 + col;
    attn_out[base]      = e0 * inv;
    attn_out[base + 8]  = e1 * inv;
    attn_out[base + 16] = e2 * inv;
    attn_out[base + 24] = e3 * inv;
  }
}

// ---------------- Kernel 3: PV ----------------
// (byte-identical to R8/R9/R10 — verified)
__global__ __launch_bounds__(256) void pv_kernel(
    const float* __restrict__ vin, const float* __restrict__ attn_in,
    float* __restrict__ out) {
  __shared__ float wpart[4][64];
  __shared__ float wsum[64];
  __shared__ float s_red[4][260];
  const int tid = threadIdx.x;
  const int bn  = blockIdx.x;
  const int wid = tid >> 6;
  const int ln  = tid & 63;

  float a0 = attn_in[(size_t)bn * 512 + tid];
  float a1 = attn_in[(size_t)bn * 512 + 256 + tid];
  wpart[wid][ln] = a0 + a1;
  __syncthreads();
  if (tid < 64) wsum[tid] = wpart[0][tid] + wpart[1][tid] + wpart[2][tid] + wpart[3][tid];
  __syncthreads();

  const float4* v4 = reinterpret_cast<const float4*>(vin) + (size_t)bn * 4096;
  float4 acc = make_float4(0.f, 0.f, 0.f, 0.f);
  #pragma unroll 8
  for (int i = 0; i < 16; ++i) {
    const int r = wid + 4 * i;
    float w = wsum[r];
    float4 vv = v4[r * 64 + ln];
    acc.x += w * vv.x; acc.y += w * vv.y; acc.z += w * vv.z; acc.w += w * vv.w;
  }
  *reinterpret_cast<float4*>(&s_red[wid][ln << 2]) = acc;
  __syncthreads();

  out[(size_t)bn * D + tid] =
      s_red[0][tid] + s_red[1][tid] + s_red[2][tid] + s_red[3][tid];
}

}  // namespace

extern "C" void kernel_launch(void* const* d_in, const int* in_sizes, int n_in,
                              void* d_out, int out_size, void* d_ws, size_t ws_size,
                              hipStream_t stream) {
  const float* q = (const float*)d_in[0];   // (8,128,1,256)
  const float* k = (const float*)d_in[1];   // (8,128,64,256)
  const float* v = (const float*)d_in[2];   // (8,128,64,256)
  const float* W = (const float*)d_in[3];   // (8,256,256)
  const float* b = (const float*)d_in[4];   // (8,)

  float* out  = (float*)d_out;              // output: 262144 f32
  float* attn = out + 262144;               // attn:   524288 f32
  char*  ws   = (char*)d_ws;
  float* qWbuf = (float*)(ws + OFF_QW);     // 8 MiB f32 qW

  hipLaunchKernelGGL(prep_kernel,    dim3(384), dim3(256), 0, stream, q, W, ws);
  hipLaunchKernelGGL(qw_mfma_kernel, dim3(256), dim3(256), 0, stream, ws, qWbuf);
  hipLaunchKernelGGL(score_kernel,   dim3(1024, 2), dim3(256), 0, stream,
                     qWbuf, k, b, attn);
  hipLaunchKernelGGL(pv_kernel,      dim3(1024), dim3(256), 0, stream,
                     v, attn, out);
}

// Round 12
// 44.695 us; speedup vs baseline: 1.1761x; 1.0620x over previous
//
#include <hip/hip_runtime.h>
#include <math.h>

namespace {

constexpr int D = 256;
constexpr int H = 8;

typedef __attribute__((ext_vector_type(8))) short bf16x8;
typedef __attribute__((ext_vector_type(4))) float f32x4;

__device__ inline unsigned short bf16rn(float x) {
  unsigned u = __builtin_bit_cast(unsigned, x);
  u += 0x7fffu + ((u >> 16) & 1u);
  return (unsigned short)(u >> 16);
}
__device__ inline float bf16tof(unsigned short b) {
  return __builtin_bit_cast(float, (unsigned)b << 16);
}

// workspace byte offsets
constexpr size_t OFF_QW  = 0;                          // 8 MiB f32 qW
constexpr size_t OFF_WFH = (size_t)8 << 20;            // 1 MiB W-frag hi
constexpr size_t OFF_WFL = (size_t)9 << 20;            // 1 MiB W-frag lo
constexpr size_t OFF_QFH = (size_t)10 << 20;           // 512 KiB q-frag hi
constexpr size_t OFF_QFL = ((size_t)10 << 20) + ((size_t)512 << 10);

// ---------------- Kernel 0: prep — bf16 hi/lo fragments of q and W ----------------
// (byte-identical to R11 — verified)
__global__ __launch_bounds__(256) void prep_kernel(
    const float* __restrict__ q, const float* __restrict__ W,
    char* __restrict__ ws) {
  const int gid = blockIdx.x * 256 + threadIdx.x;
  float e[8];
  char *hi_base, *lo_base;
  size_t outoff;
  if (gid < 65536) {          // blocks 0..255: W part
    const int l = gid & 63, ks = (gid >> 6) & 7, he = gid >> 9;
    const int h = he >> 4, et = he & 15;
    const int d0 = ks * 32 + ((l >> 4) << 3);
    const int ecol = et * 16 + (l & 15);
    const float* src = W + (size_t)h * 65536 + (size_t)d0 * 256 + ecol;
    #pragma unroll
    for (int j = 0; j < 8; ++j) e[j] = src[j * 256];
    hi_base = ws + OFF_WFH; lo_base = ws + OFF_WFL;
    outoff = (size_t)gid * 16;
  } else {                    // blocks 256..383: q part
    const int t = gid - 65536;
    const int l = t & 63, ks = (t >> 6) & 7, bt = t >> 9;
    const int row = bt * 16 + (l & 15);
    const int d0 = ks * 32 + ((l >> 4) << 3);
    const float4* src = reinterpret_cast<const float4*>(q + (size_t)row * 256 + d0);
    float4 a = src[0], b = src[1];
    e[0] = a.x; e[1] = a.y; e[2] = a.z; e[3] = a.w;
    e[4] = b.x; e[5] = b.y; e[6] = b.z; e[7] = b.w;
    hi_base = ws + OFF_QFH; lo_base = ws + OFF_QFL;
    outoff = (size_t)t * 16;
  }
  unsigned hw[4], lw[4];
  #pragma unroll
  for (int p = 0; p < 4; ++p) {
    unsigned short h0 = bf16rn(e[2 * p]), h1 = bf16rn(e[2 * p + 1]);
    unsigned short l0 = bf16rn(e[2 * p] - bf16tof(h0));
    unsigned short l1 = bf16rn(e[2 * p + 1] - bf16tof(h1));
    hw[p] = (unsigned)h0 | ((unsigned)h1 << 16);
    lw[p] = (unsigned)l0 | ((unsigned)l1 << 16);
  }
  *reinterpret_cast<uint4*>(hi_base + outoff) = make_uint4(hw[0], hw[1], hw[2], hw[3]);
  *reinterpret_cast<uint4*>(lo_base + outoff) = make_uint4(lw[0], lw[1], lw[2], lw[3]);
}

// ---------------- Kernel 1: qW via split-bf16 MFMA ----------------
// (byte-identical to R11 — verified)
__global__ __launch_bounds__(256) void qw_mfma_kernel(
    const char* __restrict__ ws_in, float* __restrict__ qW) {
  const int tid = threadIdx.x;
  const int w   = blockIdx.x * 4 + (tid >> 6);
  const int l   = tid & 63;
  const int bng = w >> 5;
  const int heg = w & 31;
  const char* qfh = ws_in + OFF_QFH;
  const char* qfl = ws_in + OFF_QFL;
  const char* wfh = ws_in + OFF_WFH;
  const char* wfl = ws_in + OFF_WFL;

  f32x4 acc[2][4];
  #pragma unroll
  for (int i = 0; i < 2; ++i)
    #pragma unroll
    for (int j = 0; j < 4; ++j) acc[i][j] = {0.f, 0.f, 0.f, 0.f};

  #pragma unroll 2
  for (int ks = 0; ks < 8; ++ks) {
    bf16x8 aH[2], aL[2], bH[4], bL[4];
    #pragma unroll
    for (int i = 0; i < 2; ++i) {
      const size_t off = ((size_t)((bng * 2 + i) * 8 + ks) * 64 + l) * 16;
      aH[i] = *reinterpret_cast<const bf16x8*>(qfh + off);
      aL[i] = *reinterpret_cast<const bf16x8*>(qfl + off);
    }
    #pragma unroll
    for (int j = 0; j < 4; ++j) {
      const size_t off = ((size_t)((heg * 4 + j) * 8 + ks) * 64 + l) * 16;
      bH[j] = *reinterpret_cast<const bf16x8*>(wfh + off);
      bL[j] = *reinterpret_cast<const bf16x8*>(wfl + off);
    }
    #pragma unroll
    for (int i = 0; i < 2; ++i)
      #pragma unroll
      for (int j = 0; j < 4; ++j) {
        acc[i][j] = __builtin_amdgcn_mfma_f32_16x16x32_bf16(aH[i], bH[j], acc[i][j], 0, 0, 0);
        acc[i][j] = __builtin_amdgcn_mfma_f32_16x16x32_bf16(aH[i], bL[j], acc[i][j], 0, 0, 0);
        acc[i][j] = __builtin_amdgcn_mfma_f32_16x16x32_bf16(aL[i], bH[j], acc[i][j], 0, 0, 0);
      }
  }

  const int rbase = (l >> 4) * 4;
  const int col   = l & 15;
  #pragma unroll
  for (int i = 0; i < 2; ++i)
    #pragma unroll
    for (int j = 0; j < 4; ++j) {
      const size_t cidx = (size_t)(heg * 4 + j) * 16 + col;
      #pragma unroll
      for (int r = 0; r < 4; ++r) {
        const int bn = (bng * 2 + i) * 16 + rbase + r;
        qW[(size_t)bn * 2048 + cidx] = acc[i][j][r];
      }
    }
}

// ---------------- Kernel 2: fused scores+softmax+PV ----------------
// Per-bn block (1024 blocks), 256 thr. Two phases (kh=0,1) reuse the R8-verified
// frag-LDS + MFMA + softmax machinery; v loads ride under the MFMA phases (T14);
// softmax emits wsum partials (pos=(row&7)*8+col, xor-32 chunk-pair sum); PV from
// registers. s_red aliases the dead frag area.
constexpr int FA_HI = 0;
constexpr int FA_LO = 16640;   // 2 tiles * 8 ks * 1040
constexpr int FB_HI = 33280;
constexpr int FB_LO = 41600;   // + 8*1040
constexpr int WSP_OFF = 49920; // float [2][64] wsum partials (by wave T)
constexpr int SMEM2 = 50432;

__global__ __launch_bounds__(256) void attn_fused_kernel(
    const float* __restrict__ qW, const float* __restrict__ kin,
    const float* __restrict__ vin, const float* __restrict__ bin,
    float* __restrict__ out, float* __restrict__ attn_out) {
  __shared__ alignas(16) long long smem_ll[SMEM2 / 8];
  char* sm = reinterpret_cast<char*>(smem_ll);
  float* wsp = reinterpret_cast<float*>(sm + WSP_OFF);   // [T][pos] flat [2*64]
  const int tid = threadIdx.x;
  const int bn  = blockIdx.x;
  const int wid = tid >> 6;
  const int ln  = tid & 63;

  const float4* k4  = reinterpret_cast<const float4*>(kin) + (size_t)bn * 4096;
  const float4* v4  = reinterpret_cast<const float4*>(vin) + (size_t)bn * 4096;
  const float4* qw4 = reinterpret_cast<const float4*>(qW) + (size_t)bn * 512;
  const float bias = bin[ln & 7];

  // ---- issue kh=0 k loads + qW loads
  float4 kv1[8];
  #pragma unroll
  for (int i = 0; i < 8; ++i) kv1[i] = k4[tid + 256 * i];
  float4 qv0 = qw4[tid];
  float4 qv1 = qw4[tid + 256];

  // ---- zero-fill unwritten B slots (cols 8-15), once
  {
    const uint4 z = make_uint4(0u, 0u, 0u, 0u);
    #pragma unroll
    for (int i = 0; i < 2; ++i) {
      int idx = tid + 256 * i;
      int region = idx >> 8;
      int rem = idx & 255;
      int ks = rem >> 5, slot = 32 + (rem & 31);
      int off = (region ? FB_LO : FB_HI) + ks * 1040 + slot * 16;
      *reinterpret_cast<uint4*>(sm + off) = z;
    }
  }

  // ---- convert helper for a k-half already in registers
  auto convert_k = [&](const float4* kv) {
    #pragma unroll
    for (int i = 0; i < 8; ++i) {
      int quad = tid + 256 * i;
      int row = quad >> 6, equad = quad & 63;
      int tile = row >> 4, lrow = row & 15;
      int ks = equad >> 3, g = (equad >> 1) & 3, j0 = (equad & 1) * 4;
      int base = tile * 8320 + ks * 1040 + (lrow * 4 + g) * 16 + j0 * 2;
      float e[4] = {kv[i].x, kv[i].y, kv[i].z, kv[i].w};
      unsigned short h0 = bf16rn(e[0]), h1 = bf16rn(e[1]),
                     h2 = bf16rn(e[2]), h3 = bf16rn(e[3]);
      unsigned short l0 = bf16rn(e[0] - bf16tof(h0)), l1 = bf16rn(e[1] - bf16tof(h1)),
                     l2 = bf16rn(e[2] - bf16tof(h2)), l3 = bf16rn(e[3] - bf16tof(h3));
      uint2 hw = make_uint2((unsigned)h0 | ((unsigned)h1 << 16),
                            (unsigned)h2 | ((unsigned)h3 << 16));
      uint2 lw = make_uint2((unsigned)l0 | ((unsigned)l1 << 16),
                            (unsigned)l2 | ((unsigned)l3 << 16));
      *reinterpret_cast<uint2*>(sm + FA_HI + base) = hw;
      *reinterpret_cast<uint2*>(sm + FA_LO + base) = lw;
    }
  };

  convert_k(kv1);
  // qW -> B frags (once; region untouched by phase-2 A writes)
  #pragma unroll
  for (int i = 0; i < 2; ++i) {
    int p = tid + 256 * i;
    int hh = p >> 6, equad = p & 63;
    int ks = equad >> 3, g = (equad >> 1) & 3, j0 = (equad & 1) * 4;
    int base = ks * 1040 + (hh * 4 + g) * 16 + j0 * 2;
    float4 qv = i == 0 ? qv0 : qv1;
    float e[4] = {qv.x, qv.y, qv.z, qv.w};
    unsigned short h0 = bf16rn(e[0]), h1 = bf16rn(e[1]),
                   h2 = bf16rn(e[2]), h3 = bf16rn(e[3]);
    unsigned short l0 = bf16rn(e[0] - bf16tof(h0)), l1 = bf16rn(e[1] - bf16tof(h1)),
                   l2 = bf16rn(e[2] - bf16tof(h2)), l3 = bf16rn(e[3] - bf16tof(h3));
    uint2 hw = make_uint2((unsigned)h0 | ((unsigned)h1 << 16),
                          (unsigned)h2 | ((unsigned)h3 << 16));
    uint2 lw = make_uint2((unsigned)l0 | ((unsigned)l1 << 16),
                          (unsigned)l2 | ((unsigned)l3 << 16));
    *reinterpret_cast<uint2*>(sm + FB_HI + base) = hw;
    *reinterpret_cast<uint2*>(sm + FB_LO + base) = lw;
  }

  // ---- issue kh=1 k loads + v rows 0..31 (ride under phase-1 compute)
  float4 kv2[8];
  #pragma unroll
  for (int i = 0; i < 8; ++i) kv2[i] = k4[2048 + tid + 256 * i];
  float4 vva[8];
  #pragma unroll
  for (int i = 0; i < 8; ++i) vva[i] = v4[(wid + 4 * i) * 64 + ln];
  __builtin_amdgcn_sched_barrier(0);
  __syncthreads();

  // ---- MFMA + softmax + attn write + wsum-partial, per phase
  auto do_phase = [&](int kh, bool first) {
    const int T = wid;
    const int slot_r = (ln & 15) * 4 + (ln >> 4);
    const char* paH = sm + FA_HI + T * 8320 + slot_r * 16;
    const char* paL = sm + FA_LO + T * 8320 + slot_r * 16;
    const char* pbH = sm + FB_HI + slot_r * 16;
    const char* pbL = sm + FB_LO + slot_r * 16;
    f32x4 acc = {0.f, 0.f, 0.f, 0.f};
    #pragma unroll
    for (int ks = 0; ks < 8; ++ks) {
      bf16x8 aH = *reinterpret_cast<const bf16x8*>(paH + ks * 1040);
      bf16x8 aL = *reinterpret_cast<const bf16x8*>(paL + ks * 1040);
      bf16x8 bH = *reinterpret_cast<const bf16x8*>(pbH + ks * 1040);
      bf16x8 bL = *reinterpret_cast<const bf16x8*>(pbL + ks * 1040);
      acc = __builtin_amdgcn_mfma_f32_16x16x32_bf16(aH, bH, acc, 0, 0, 0);
      acc = __builtin_amdgcn_mfma_f32_16x16x32_bf16(aH, bL, acc, 0, 0, 0);
      acc = __builtin_amdgcn_mfma_f32_16x16x32_bf16(aL, bH, acc, 0, 0, 0);
    }
    const int col = ln & 15;
    const bool valid = col < 8;
    float x0 = acc[0] + bias, x1 = acc[1] + bias, x2 = acc[2] + bias, x3 = acc[3] + bias;
    float m = valid ? fmaxf(fmaxf(x0, x1), fmaxf(x2, x3)) : -1e30f;
    m = fmaxf(m, __shfl_xor(m, 1, 64));
    m = fmaxf(m, __shfl_xor(m, 2, 64));
    m = fmaxf(m, __shfl_xor(m, 4, 64));
    m = fmaxf(m, __shfl_xor(m, 16, 64));
    float e0 = valid ? expf(x0 - m) : 0.f;
    float e1 = valid ? expf(x1 - m) : 0.f;
    float e2 = valid ? expf(x2 - m) : 0.f;
    float e3 = valid ? expf(x3 - m) : 0.f;
    float s = e0 + e1 + e2 + e3;
    s += __shfl_xor(s, 1, 64);
    s += __shfl_xor(s, 2, 64);
    s += __shfl_xor(s, 4, 64);
    s += __shfl_xor(s, 16, 64);
    float inv = 1.f / s;
    float p0 = e0 * inv, p1 = e1 * inv, p2 = e2 * inv, p3 = e3 * inv;
    if (valid) {
      size_t base = (size_t)bn * 512 + (size_t)(kh * 32 + T * 16 + (ln >> 4) * 4) * 8 + col;
      attn_out[base]      = p0;
      attn_out[base + 8]  = p1;
      attn_out[base + 16] = p2;
      attn_out[base + 24] = p3;
    }
    // wsum partial: pos=(row&7)*8+col, sum chunk-pair via xor-32; one writer/pos.
    p0 += __shfl_xor(p0, 32, 64);
    p1 += __shfl_xor(p1, 32, 64);
    p2 += __shfl_xor(p2, 32, 64);
    p3 += __shfl_xor(p3, 32, 64);
    if (ln < 32 && (ln & 15) < 8) {
      const int rb = (ln >> 4) * 4;     // 0 or 4
      const int c8 = ln & 7;
      float* w = wsp + T * 64;
      if (first) {
        w[(rb + 0) * 8 + c8] = p0;
        w[(rb + 1) * 8 + c8] = p1;
        w[(rb + 2) * 8 + c8] = p2;
        w[(rb + 3) * 8 + c8] = p3;
      } else {
        w[(rb + 0) * 8 + c8] += p0;
        w[(rb + 1) * 8 + c8] += p1;
        w[(rb + 2) * 8 + c8] += p2;
        w[(rb + 3) * 8 + c8] += p3;
      }
    }
  };

  if (wid < 2) do_phase(0, true);
  __syncthreads();          // phase-1 LDS reads done; wsp visible later

  convert_k(kv2);           // overwrite A-frag region for kh=1
  float4 vvb[8];
  #pragma unroll
  for (int i = 0; i < 8; ++i) vvb[i] = v4[(32 + wid + 4 * i) * 64 + ln];
  __builtin_amdgcn_sched_barrier(0);
  __syncthreads();

  if (wid < 2) do_phase(1, false);
  __syncthreads();          // all wsp complete; frag area dead

  // ---- PV from registers
  float4 acc = make_float4(0.f, 0.f, 0.f, 0.f);
  #pragma unroll
  for (int i = 0; i < 8; ++i) {
    const int r = wid + 4 * i;
    float w = wsp[r] + wsp[64 + r];
    acc.x += w * vva[i].x; acc.y += w * vva[i].y;
    acc.z += w * vva[i].z; acc.w += w * vva[i].w;
  }
  #pragma unroll
  for (int i = 0; i < 8; ++i) {
    const int r = 32 + wid + 4 * i;
    float w = wsp[r] + wsp[64 + r];
    acc.x += w * vvb[i].x; acc.y += w * vvb[i].y;
    acc.z += w * vvb[i].z; acc.w += w * vvb[i].w;
  }
  float* s_red = reinterpret_cast<float*>(sm);   // [4][260] alias on dead frag area
  *reinterpret_cast<float4*>(&s_red[wid * 260 + (ln << 2)]) = acc;
  __syncthreads();

  out[(size_t)bn * D + tid] =
      s_red[tid] + s_red[260 + tid] + s_red[520 + tid] + s_red[780 + tid];
}

}  // namespace

extern "C" void kernel_launch(void* const* d_in, const int* in_sizes, int n_in,
                              void* d_out, int out_size, void* d_ws, size_t ws_size,
                              hipStream_t stream) {
  const float* q = (const float*)d_in[0];   // (8,128,1,256)
  const float* k = (const float*)d_in[1];   // (8,128,64,256)
  const float* v = (const float*)d_in[2];   // (8,128,64,256)
  const float* W = (const float*)d_in[3];   // (8,256,256)
  const float* b = (const float*)d_in[4];   // (8,)

  float* out  = (float*)d_out;              // output: 262144 f32
  float* attn = out + 262144;               // attn:   524288 f32
  char*  ws   = (char*)d_ws;
  float* qWbuf = (float*)(ws + OFF_QW);     // 8 MiB f32 qW

  hipLaunchKernelGGL(prep_kernel,       dim3(384),  dim3(256), 0, stream, q, W, ws);
  hipLaunchKernelGGL(qw_mfma_kernel,    dim3(256),  dim3(256), 0, stream, ws, qWbuf);
  hipLaunchKernelGGL(attn_fused_kernel, dim3(1024), dim3(256), 0, stream,
                     qWbuf, k, v, b, out, attn);
}

// Round 13
// 43.533 us; speedup vs baseline: 1.2075x; 1.0267x over previous
//
#include <hip/hip_runtime.h>
#include <math.h>

namespace {

constexpr int D = 256;
constexpr int H = 8;

typedef __attribute__((ext_vector_type(8))) short bf16x8;
typedef __attribute__((ext_vector_type(4))) float f32x4;

__device__ inline unsigned short bf16rn(float x) {
  unsigned u = __builtin_bit_cast(unsigned, x);
  u += 0x7fffu + ((u >> 16) & 1u);
  return (unsigned short)(u >> 16);
}
__device__ inline float bf16tof(unsigned short b) {
  return __builtin_bit_cast(float, (unsigned)b << 16);
}

// workspace byte offsets
constexpr size_t OFF_QW  = 0;                          // 8 MiB f32 qW
constexpr size_t OFF_WFH = (size_t)8 << 20;            // 1 MiB W-frag hi
constexpr size_t OFF_WFL = (size_t)9 << 20;            // 1 MiB W-frag lo
constexpr size_t OFF_QFH = (size_t)10 << 20;           // 512 KiB q-frag hi
constexpr size_t OFF_QFL = ((size_t)10 << 20) + ((size_t)512 << 10);

// ---------------- Kernel 0: prep — bf16 hi/lo fragments of q and W ----------------
// (byte-identical to R11/R12 — verified)
__global__ __launch_bounds__(256) void prep_kernel(
    const float* __restrict__ q, const float* __restrict__ W,
    char* __restrict__ ws) {
  const int gid = blockIdx.x * 256 + threadIdx.x;
  float e[8];
  char *hi_base, *lo_base;
  size_t outoff;
  if (gid < 65536) {          // blocks 0..255: W part
    const int l = gid & 63, ks = (gid >> 6) & 7, he = gid >> 9;
    const int h = he >> 4, et = he & 15;
    const int d0 = ks * 32 + ((l >> 4) << 3);
    const int ecol = et * 16 + (l & 15);
    const float* src = W + (size_t)h * 65536 + (size_t)d0 * 256 + ecol;
    #pragma unroll
    for (int j = 0; j < 8; ++j) e[j] = src[j * 256];
    hi_base = ws + OFF_WFH; lo_base = ws + OFF_WFL;
    outoff = (size_t)gid * 16;
  } else {                    // blocks 256..383: q part
    const int t = gid - 65536;
    const int l = t & 63, ks = (t >> 6) & 7, bt = t >> 9;
    const int row = bt * 16 + (l & 15);
    const int d0 = ks * 32 + ((l >> 4) << 3);
    const float4* src = reinterpret_cast<const float4*>(q + (size_t)row * 256 + d0);
    float4 a = src[0], b = src[1];
    e[0] = a.x; e[1] = a.y; e[2] = a.z; e[3] = a.w;
    e[4] = b.x; e[5] = b.y; e[6] = b.z; e[7] = b.w;
    hi_base = ws + OFF_QFH; lo_base = ws + OFF_QFL;
    outoff = (size_t)t * 16;
  }
  unsigned hw[4], lw[4];
  #pragma unroll
  for (int p = 0; p < 4; ++p) {
    unsigned short h0 = bf16rn(e[2 * p]), h1 = bf16rn(e[2 * p + 1]);
    unsigned short l0 = bf16rn(e[2 * p] - bf16tof(h0));
    unsigned short l1 = bf16rn(e[2 * p + 1] - bf16tof(h1));
    hw[p] = (unsigned)h0 | ((unsigned)h1 << 16);
    lw[p] = (unsigned)l0 | ((unsigned)l1 << 16);
  }
  *reinterpret_cast<uint4*>(hi_base + outoff) = make_uint4(hw[0], hw[1], hw[2], hw[3]);
  *reinterpret_cast<uint4*>(lo_base + outoff) = make_uint4(lw[0], lw[1], lw[2], lw[3]);
}

// ---------------- Kernel 1: qW via split-bf16 MFMA ----------------
// (byte-identical to R11/R12 — verified; keeps f32-grade qW)
__global__ __launch_bounds__(256) void qw_mfma_kernel(
    const char* __restrict__ ws_in, float* __restrict__ qW) {
  const int tid = threadIdx.x;
  const int w   = blockIdx.x * 4 + (tid >> 6);
  const int l   = tid & 63;
  const int bng = w >> 5;
  const int heg = w & 31;
  const char* qfh = ws_in + OFF_QFH;
  const char* qfl = ws_in + OFF_QFL;
  const char* wfh = ws_in + OFF_WFH;
  const char* wfl = ws_in + OFF_WFL;

  f32x4 acc[2][4];
  #pragma unroll
  for (int i = 0; i < 2; ++i)
    #pragma unroll
    for (int j = 0; j < 4; ++j) acc[i][j] = {0.f, 0.f, 0.f, 0.f};

  #pragma unroll 2
  for (int ks = 0; ks < 8; ++ks) {
    bf16x8 aH[2], aL[2], bH[4], bL[4];
    #pragma unroll
    for (int i = 0; i < 2; ++i) {
      const size_t off = ((size_t)((bng * 2 + i) * 8 + ks) * 64 + l) * 16;
      aH[i] = *reinterpret_cast<const bf16x8*>(qfh + off);
      aL[i] = *reinterpret_cast<const bf16x8*>(qfl + off);
    }
    #pragma unroll
    for (int j = 0; j < 4; ++j) {
      const size_t off = ((size_t)((heg * 4 + j) * 8 + ks) * 64 + l) * 16;
      bH[j] = *reinterpret_cast<const bf16x8*>(wfh + off);
      bL[j] = *reinterpret_cast<const bf16x8*>(wfl + off);
    }
    #pragma unroll
    for (int i = 0; i < 2; ++i)
      #pragma unroll
      for (int j = 0; j < 4; ++j) {
        acc[i][j] = __builtin_amdgcn_mfma_f32_16x16x32_bf16(aH[i], bH[j], acc[i][j], 0, 0, 0);
        acc[i][j] = __builtin_amdgcn_mfma_f32_16x16x32_bf16(aH[i], bL[j], acc[i][j], 0, 0, 0);
        acc[i][j] = __builtin_amdgcn_mfma_f32_16x16x32_bf16(aL[i], bH[j], acc[i][j], 0, 0, 0);
      }
  }

  const int rbase = (l >> 4) * 4;
  const int col   = l & 15;
  #pragma unroll
  for (int i = 0; i < 2; ++i)
    #pragma unroll
    for (int j = 0; j < 4; ++j) {
      const size_t cidx = (size_t)(heg * 4 + j) * 16 + col;
      #pragma unroll
      for (int r = 0; r < 4; ++r) {
        const int bn = (bng * 2 + i) * 16 + rbase + r;
        qW[(size_t)bn * 2048 + cidx] = acc[i][j][r];
      }
    }
}

// ---------------- Kernel 2: fused scores+softmax+PV (hi-only bf16 scores) --------
// Per-bn block (1024), 256 thr, __launch_bounds__(256,4) -> VGPR<=128, 4 blk/CU.
// LDS 25.5 KB: A-hi 2 tiles (16640) + B-hi (8320) + wsum partials (512).
// Same R8-verified frag placement / C-layout / wsum mapping; 1 MFMA per ks.
constexpr int FA_HI = 0;
constexpr int FB_HI = 16640;   // 2 tiles * 8 ks * 1040
constexpr int WSP_OFF = 24960; // float [2][64] wsum partials (by wave T)
constexpr int SMEM2 = 25472;

__global__ __launch_bounds__(256, 4) void attn_fused_kernel(
    const float* __restrict__ qW, const float* __restrict__ kin,
    const float* __restrict__ vin, const float* __restrict__ bin,
    float* __restrict__ out, float* __restrict__ attn_out) {
  __shared__ alignas(16) long long smem_ll[SMEM2 / 8];
  char* sm = reinterpret_cast<char*>(smem_ll);
  float* wsp = reinterpret_cast<float*>(sm + WSP_OFF);   // flat [2*64]
  const int tid = threadIdx.x;
  const int bn  = blockIdx.x;
  const int wid = tid >> 6;
  const int ln  = tid & 63;

  const float4* k4  = reinterpret_cast<const float4*>(kin) + (size_t)bn * 4096;
  const float4* v4  = reinterpret_cast<const float4*>(vin) + (size_t)bn * 4096;
  const float4* qw4 = reinterpret_cast<const float4*>(qW) + (size_t)bn * 512;
  const float bias = bin[ln & 7];

  // ---- issue kh=0 k loads + qW loads
  float4 kv1[8];
  #pragma unroll
  for (int i = 0; i < 8; ++i) kv1[i] = k4[tid + 256 * i];
  float4 qv0 = qw4[tid];
  float4 qv1 = qw4[tid + 256];

  // ---- zero-fill unwritten B-hi slots (cols 8-15): one uint4 per thread
  {
    const int ks = tid >> 5, slot = 32 + (tid & 31);
    *reinterpret_cast<uint4*>(sm + FB_HI + ks * 1040 + slot * 16) =
        make_uint4(0u, 0u, 0u, 0u);
  }

  // ---- convert helper: k-half in regs -> A-hi frags in LDS
  auto convert_k = [&](const float4* kv) {
    #pragma unroll
    for (int i = 0; i < 8; ++i) {
      int quad = tid + 256 * i;
      int row = quad >> 6, equad = quad & 63;
      int tile = row >> 4, lrow = row & 15;
      int ks = equad >> 3, g = (equad >> 1) & 3, j0 = (equad & 1) * 4;
      int base = tile * 8320 + ks * 1040 + (lrow * 4 + g) * 16 + j0 * 2;
      unsigned short h0 = bf16rn(kv[i].x), h1 = bf16rn(kv[i].y),
                     h2 = bf16rn(kv[i].z), h3 = bf16rn(kv[i].w);
      uint2 hw = make_uint2((unsigned)h0 | ((unsigned)h1 << 16),
                            (unsigned)h2 | ((unsigned)h3 << 16));
      *reinterpret_cast<uint2*>(sm + FA_HI + base) = hw;
    }
  };

  convert_k(kv1);
  // qW -> B-hi frags (once)
  #pragma unroll
  for (int i = 0; i < 2; ++i) {
    int p = tid + 256 * i;
    int hh = p >> 6, equad = p & 63;
    int ks = equad >> 3, g = (equad >> 1) & 3, j0 = (equad & 1) * 4;
    int base = ks * 1040 + (hh * 4 + g) * 16 + j0 * 2;
    float4 qv = i == 0 ? qv0 : qv1;
    unsigned short h0 = bf16rn(qv.x), h1 = bf16rn(qv.y),
                   h2 = bf16rn(qv.z), h3 = bf16rn(qv.w);
    uint2 hw = make_uint2((unsigned)h0 | ((unsigned)h1 << 16),
                          (unsigned)h2 | ((unsigned)h3 << 16));
    *reinterpret_cast<uint2*>(sm + FB_HI + base) = hw;
  }

  // ---- issue kh=1 k loads (ride under phase-0 compute)
  float4 kv2[8];
  #pragma unroll
  for (int i = 0; i < 8; ++i) kv2[i] = k4[2048 + tid + 256 * i];
  __builtin_amdgcn_sched_barrier(0);
  __syncthreads();

  // ---- MFMA + softmax + attn write + wsum-partial, per phase
  auto do_phase = [&](int kh, bool first) {
    const int T = wid;
    const int slot_r = (ln & 15) * 4 + (ln >> 4);
    const char* paH = sm + FA_HI + T * 8320 + slot_r * 16;
    const char* pbH = sm + FB_HI + slot_r * 16;
    f32x4 acc = {0.f, 0.f, 0.f, 0.f};
    #pragma unroll
    for (int ks = 0; ks < 8; ++ks) {
      bf16x8 aH = *reinterpret_cast<const bf16x8*>(paH + ks * 1040);
      bf16x8 bH = *reinterpret_cast<const bf16x8*>(pbH + ks * 1040);
      acc = __builtin_amdgcn_mfma_f32_16x16x32_bf16(aH, bH, acc, 0, 0, 0);
    }
    const int col = ln & 15;
    const bool valid = col < 8;
    float x0 = acc[0] + bias, x1 = acc[1] + bias, x2 = acc[2] + bias, x3 = acc[3] + bias;
    float m = valid ? fmaxf(fmaxf(x0, x1), fmaxf(x2, x3)) : -1e30f;
    m = fmaxf(m, __shfl_xor(m, 1, 64));
    m = fmaxf(m, __shfl_xor(m, 2, 64));
    m = fmaxf(m, __shfl_xor(m, 4, 64));
    m = fmaxf(m, __shfl_xor(m, 16, 64));
    float e0 = valid ? expf(x0 - m) : 0.f;
    float e1 = valid ? expf(x1 - m) : 0.f;
    float e2 = valid ? expf(x2 - m) : 0.f;
    float e3 = valid ? expf(x3 - m) : 0.f;
    float s = e0 + e1 + e2 + e3;
    s += __shfl_xor(s, 1, 64);
    s += __shfl_xor(s, 2, 64);
    s += __shfl_xor(s, 4, 64);
    s += __shfl_xor(s, 16, 64);
    float inv = 1.f / s;
    float p0 = e0 * inv, p1 = e1 * inv, p2 = e2 * inv, p3 = e3 * inv;
    if (valid) {
      size_t base = (size_t)bn * 512 + (size_t)(kh * 32 + T * 16 + (ln >> 4) * 4) * 8 + col;
      attn_out[base]      = p0;
      attn_out[base + 8]  = p1;
      attn_out[base + 16] = p2;
      attn_out[base + 24] = p3;
    }
    // wsum partial: pos=(row&7)*8+col, chunk-pair sum via xor-32; one writer/pos.
    p0 += __shfl_xor(p0, 32, 64);
    p1 += __shfl_xor(p1, 32, 64);
    p2 += __shfl_xor(p2, 32, 64);
    p3 += __shfl_xor(p3, 32, 64);
    if (ln < 32 && (ln & 15) < 8) {
      const int rb = (ln >> 4) * 4;
      const int c8 = ln & 7;
      float* w = wsp + T * 64;
      if (first) {
        w[(rb + 0) * 8 + c8] = p0;
        w[(rb + 1) * 8 + c8] = p1;
        w[(rb + 2) * 8 + c8] = p2;
        w[(rb + 3) * 8 + c8] = p3;
      } else {
        w[(rb + 0) * 8 + c8] += p0;
        w[(rb + 1) * 8 + c8] += p1;
        w[(rb + 2) * 8 + c8] += p2;
        w[(rb + 3) * 8 + c8] += p3;
      }
    }
  };

  if (wid < 2) do_phase(0, true);
  __syncthreads();          // phase-0 LDS reads done

  convert_k(kv2);           // overwrite A-hi region for kh=1
  // ---- issue all v loads (rows == wid mod 4); waves 2-3 issue early,
  // waves 0-1 issue before entering phase-1 MFMA (loads ride under it)
  float4 vv[16];
  #pragma unroll
  for (int i = 0; i < 16; ++i) vv[i] = v4[(wid + 4 * i) * 64 + ln];
  __builtin_amdgcn_sched_barrier(0);
  __syncthreads();

  if (wid < 2) do_phase(1, false);
  __syncthreads();          // all wsp complete; frag area dead

  // ---- PV from registers
  float4 acc = make_float4(0.f, 0.f, 0.f, 0.f);
  #pragma unroll
  for (int i = 0; i < 16; ++i) {
    const int r = wid + 4 * i;
    float w = wsp[r] + wsp[64 + r];
    acc.x += w * vv[i].x; acc.y += w * vv[i].y;
    acc.z += w * vv[i].z; acc.w += w * vv[i].w;
  }
  float* s_red = reinterpret_cast<float*>(sm);   // [4][260] alias on dead frag area
  *reinterpret_cast<float4*>(&s_red[wid * 260 + (ln << 2)]) = acc;
  __syncthreads();

  out[(size_t)bn * D + tid] =
      s_red[tid] + s_red[260 + tid] + s_red[520 + tid] + s_red[780 + tid];
}

}  // namespace

extern "C" void kernel_launch(void* const* d_in, const int* in_sizes, int n_in,
                              void* d_out, int out_size, void* d_ws, size_t ws_size,
                              hipStream_t stream) {
  const float* q = (const float*)d_in[0];   // (8,128,1,256)
  const float* k = (const float*)d_in[1];   // (8,128,64,256)
  const float* v = (const float*)d_in[2];   // (8,128,64,256)
  const float* W = (const float*)d_in[3];   // (8,256,256)
  const float* b = (const float*)d_in[4];   // (8,)

  float* out  = (float*)d_out;              // output: 262144 f32
  float* attn = out + 262144;               // attn:   524288 f32
  char*  ws   = (char*)d_ws;
  float* qWbuf = (float*)(ws + OFF_QW);     // 8 MiB f32 qW

  hipLaunchKernelGGL(prep_kernel,       dim3(384),  dim3(256), 0, stream, q, W, ws);
  hipLaunchKernelGGL(qw_mfma_kernel,    dim3(256),  dim3(256), 0, stream, ws, qWbuf);
  hipLaunchKernelGGL(attn_fused_kernel, dim3(1024), dim3(256), 0, stream,
                     qWbuf, k, v, b, out, attn);
}

// Round 14
// 42.239 us; speedup vs baseline: 1.2445x; 1.0306x over previous
//
#include <hip/hip_runtime.h>
#include <math.h>

namespace {

constexpr int D = 256;
constexpr int H = 8;

typedef __attribute__((ext_vector_type(8))) short bf16x8;
typedef __attribute__((ext_vector_type(4))) float f32x4;

__device__ inline unsigned short bf16rn(float x) {
  unsigned u = __builtin_bit_cast(unsigned, x);
  u += 0x7fffu + ((u >> 16) & 1u);
  return (unsigned short)(u >> 16);
}
__device__ inline float bf16tof(unsigned short b) {
  return __builtin_bit_cast(float, (unsigned)b << 16);
}

// workspace byte offsets
constexpr size_t OFF_QW  = 0;                          // 8 MiB f32 qW
constexpr size_t OFF_WFH = (size_t)8 << 20;            // 1 MiB W-frag hi
constexpr size_t OFF_WFL = (size_t)9 << 20;            // 1 MiB W-frag lo
constexpr size_t OFF_QFH = (size_t)10 << 20;           // 512 KiB q-frag hi
constexpr size_t OFF_QFL = ((size_t)10 << 20) + ((size_t)512 << 10);

// ---------------- Kernel 0: prep — bf16 hi/lo fragments of q and W ----------------
// (byte-identical to R11-R13 — verified)
__global__ __launch_bounds__(256) void prep_kernel(
    const float* __restrict__ q, const float* __restrict__ W,
    char* __restrict__ ws) {
  const int gid = blockIdx.x * 256 + threadIdx.x;
  float e[8];
  char *hi_base, *lo_base;
  size_t outoff;
  if (gid < 65536) {          // blocks 0..255: W part
    const int l = gid & 63, ks = (gid >> 6) & 7, he = gid >> 9;
    const int h = he >> 4, et = he & 15;
    const int d0 = ks * 32 + ((l >> 4) << 3);
    const int ecol = et * 16 + (l & 15);
    const float* src = W + (size_t)h * 65536 + (size_t)d0 * 256 + ecol;
    #pragma unroll
    for (int j = 0; j < 8; ++j) e[j] = src[j * 256];
    hi_base = ws + OFF_WFH; lo_base = ws + OFF_WFL;
    outoff = (size_t)gid * 16;
  } else {                    // blocks 256..383: q part
    const int t = gid - 65536;
    const int l = t & 63, ks = (t >> 6) & 7, bt = t >> 9;
    const int row = bt * 16 + (l & 15);
    const int d0 = ks * 32 + ((l >> 4) << 3);
    const float4* src = reinterpret_cast<const float4*>(q + (size_t)row * 256 + d0);
    float4 a = src[0], b = src[1];
    e[0] = a.x; e[1] = a.y; e[2] = a.z; e[3] = a.w;
    e[4] = b.x; e[5] = b.y; e[6] = b.z; e[7] = b.w;
    hi_base = ws + OFF_QFH; lo_base = ws + OFF_QFL;
    outoff = (size_t)t * 16;
  }
  unsigned hw[4], lw[4];
  #pragma unroll
  for (int p = 0; p < 4; ++p) {
    unsigned short h0 = bf16rn(e[2 * p]), h1 = bf16rn(e[2 * p + 1]);
    unsigned short l0 = bf16rn(e[2 * p] - bf16tof(h0));
    unsigned short l1 = bf16rn(e[2 * p + 1] - bf16tof(h1));
    hw[p] = (unsigned)h0 | ((unsigned)h1 << 16);
    lw[p] = (unsigned)l0 | ((unsigned)l1 << 16);
  }
  *reinterpret_cast<uint4*>(hi_base + outoff) = make_uint4(hw[0], hw[1], hw[2], hw[3]);
  *reinterpret_cast<uint4*>(lo_base + outoff) = make_uint4(lw[0], lw[1], lw[2], lw[3]);
}

// ---------------- Kernel 1: qW via split-bf16 MFMA ----------------
// (byte-identical to R11-R13 — verified; keeps f32-grade qW)
__global__ __launch_bounds__(256) void qw_mfma_kernel(
    const char* __restrict__ ws_in, float* __restrict__ qW) {
  const int tid = threadIdx.x;
  const int w   = blockIdx.x * 4 + (tid >> 6);
  const int l   = tid & 63;
  const int bng = w >> 5;
  const int heg = w & 31;
  const char* qfh = ws_in + OFF_QFH;
  const char* qfl = ws_in + OFF_QFL;
  const char* wfh = ws_in + OFF_WFH;
  const char* wfl = ws_in + OFF_WFL;

  f32x4 acc[2][4];
  #pragma unroll
  for (int i = 0; i < 2; ++i)
    #pragma unroll
    for (int j = 0; j < 4; ++j) acc[i][j] = {0.f, 0.f, 0.f, 0.f};

  #pragma unroll 2
  for (int ks = 0; ks < 8; ++ks) {
    bf16x8 aH[2], aL[2], bH[4], bL[4];
    #pragma unroll
    for (int i = 0; i < 2; ++i) {
      const size_t off = ((size_t)((bng * 2 + i) * 8 + ks) * 64 + l) * 16;
      aH[i] = *reinterpret_cast<const bf16x8*>(qfh + off);
      aL[i] = *reinterpret_cast<const bf16x8*>(qfl + off);
    }
    #pragma unroll
    for (int j = 0; j < 4; ++j) {
      const size_t off = ((size_t)((heg * 4 + j) * 8 + ks) * 64 + l) * 16;
      bH[j] = *reinterpret_cast<const bf16x8*>(wfh + off);
      bL[j] = *reinterpret_cast<const bf16x8*>(wfl + off);
    }
    #pragma unroll
    for (int i = 0; i < 2; ++i)
      #pragma unroll
      for (int j = 0; j < 4; ++j) {
        acc[i][j] = __builtin_amdgcn_mfma_f32_16x16x32_bf16(aH[i], bH[j], acc[i][j], 0, 0, 0);
        acc[i][j] = __builtin_amdgcn_mfma_f32_16x16x32_bf16(aH[i], bL[j], acc[i][j], 0, 0, 0);
        acc[i][j] = __builtin_amdgcn_mfma_f32_16x16x32_bf16(aL[i], bH[j], acc[i][j], 0, 0, 0);
      }
  }

  const int rbase = (l >> 4) * 4;
  const int col   = l & 15;
  #pragma unroll
  for (int i = 0; i < 2; ++i)
    #pragma unroll
    for (int j = 0; j < 4; ++j) {
      const size_t cidx = (size_t)(heg * 4 + j) * 16 + col;
      #pragma unroll
      for (int r = 0; r < 4; ++r) {
        const int bn = (bng * 2 + i) * 16 + rbase + r;
        qW[(size_t)bn * 2048 + cidx] = acc[i][j][r];
      }
    }
}

// ---------------- Kernel 2: fused scores+softmax+PV (A-direct, 1 phase) ----------
// Per-bn block (1024), 256 thr = 4 waves, each wave = tile T=wid (16 k-rows, K=256).
// A-frags loaded DIRECTLY from global k in fragment order (lane l: row T*16+(l&15),
// f32 cols ks*32+(l>>4)*8 .. +8) — same k-placement as B-frags (verified bijection),
// no k-LDS, no phases, no idle waves. LDS 9.3 KB: B-hi frags (8320) + wsp (1024).
// Softmax / C-layout / wsp mapping byte-level identical to R13 (verified).
constexpr int FB2   = 0;
constexpr int WSP2  = 8320;
constexpr int SMEM3 = 9344;

__global__ __launch_bounds__(256, 4) void attn_fused_kernel(
    const float* __restrict__ qW, const float* __restrict__ kin,
    const float* __restrict__ vin, const float* __restrict__ bin,
    float* __restrict__ out, float* __restrict__ attn_out) {
  __shared__ alignas(16) long long smem_ll[SMEM3 / 8];
  char* sm = reinterpret_cast<char*>(smem_ll);
  float* wsp = reinterpret_cast<float*>(sm + WSP2);   // flat [4*64]
  const int tid = threadIdx.x;
  const int bn  = blockIdx.x;
  const int wid = tid >> 6;
  const int ln  = tid & 63;

  // ---- A-direct loads: 16 independent float4 (fragment-ordered addresses)
  const float* arow = kin + (size_t)bn * 16384 +
                      (size_t)(wid * 16 + (ln & 15)) * 256 + ((ln >> 4) << 3);
  float4 ka[16];
  #pragma unroll
  for (int ks = 0; ks < 8; ++ks) {
    ka[2 * ks]     = *reinterpret_cast<const float4*>(arow + ks * 32);
    ka[2 * ks + 1] = *reinterpret_cast<const float4*>(arow + ks * 32 + 4);
  }
  const float4* qw4 = reinterpret_cast<const float4*>(qW) + (size_t)bn * 512;
  float4 qv0 = qw4[tid];
  float4 qv1 = qw4[tid + 256];

  // ---- zero-fill unwritten B slots (cols 8-15)
  {
    const int ks = tid >> 5, slot = 32 + (tid & 31);
    *reinterpret_cast<uint4*>(sm + FB2 + ks * 1040 + slot * 16) =
        make_uint4(0u, 0u, 0u, 0u);
  }
  // ---- qW -> B-hi frags (R13-verified placement)
  #pragma unroll
  for (int i = 0; i < 2; ++i) {
    int p = tid + 256 * i;
    int hh = p >> 6, equad = p & 63;
    int ks = equad >> 3, g = (equad >> 1) & 3, j0 = (equad & 1) * 4;
    int base = FB2 + ks * 1040 + (hh * 4 + g) * 16 + j0 * 2;
    float4 qv = i == 0 ? qv0 : qv1;
    unsigned short h0 = bf16rn(qv.x), h1 = bf16rn(qv.y),
                   h2 = bf16rn(qv.z), h3 = bf16rn(qv.w);
    *reinterpret_cast<uint2*>(sm + base) =
        make_uint2((unsigned)h0 | ((unsigned)h1 << 16),
                   (unsigned)h2 | ((unsigned)h3 << 16));
  }
  __syncthreads();

  // ---- MFMA over full K=256, tile T = wid
  const int slot_r = (ln & 15) * 4 + (ln >> 4);
  const char* pbH = sm + FB2 + slot_r * 16;
  f32x4 acc = {0.f, 0.f, 0.f, 0.f};
  #pragma unroll
  for (int ks = 0; ks < 8; ++ks) {
    const float4 a0 = ka[2 * ks], a1 = ka[2 * ks + 1];
    bf16x8 aH;
    aH[0] = (short)bf16rn(a0.x); aH[1] = (short)bf16rn(a0.y);
    aH[2] = (short)bf16rn(a0.z); aH[3] = (short)bf16rn(a0.w);
    aH[4] = (short)bf16rn(a1.x); aH[5] = (short)bf16rn(a1.y);
    aH[6] = (short)bf16rn(a1.z); aH[7] = (short)bf16rn(a1.w);
    bf16x8 bH = *reinterpret_cast<const bf16x8*>(pbH + ks * 1040);
    acc = __builtin_amdgcn_mfma_f32_16x16x32_bf16(aH, bH, acc, 0, 0, 0);
  }

  // ---- softmax on C-frags (chunk = 2*wid + (ln>=32); R13-verified reduce)
  const float bias = bin[ln & 7];
  const int col = ln & 15;
  const bool valid = col < 8;
  float x0 = acc[0] + bias, x1 = acc[1] + bias, x2 = acc[2] + bias, x3 = acc[3] + bias;
  float m = valid ? fmaxf(fmaxf(x0, x1), fmaxf(x2, x3)) : -1e30f;
  m = fmaxf(m, __shfl_xor(m, 1, 64));
  m = fmaxf(m, __shfl_xor(m, 2, 64));
  m = fmaxf(m, __shfl_xor(m, 4, 64));
  m = fmaxf(m, __shfl_xor(m, 16, 64));
  float e0 = valid ? expf(x0 - m) : 0.f;
  float e1 = valid ? expf(x1 - m) : 0.f;
  float e2 = valid ? expf(x2 - m) : 0.f;
  float e3 = valid ? expf(x3 - m) : 0.f;
  float s = e0 + e1 + e2 + e3;
  s += __shfl_xor(s, 1, 64);
  s += __shfl_xor(s, 2, 64);
  s += __shfl_xor(s, 4, 64);
  s += __shfl_xor(s, 16, 64);
  float inv = 1.f / s;
  float p0 = e0 * inv, p1 = e1 * inv, p2 = e2 * inv, p3 = e3 * inv;
  if (valid) {
    size_t base = (size_t)bn * 512 + (size_t)(wid * 16 + (ln >> 4) * 4) * 8 + col;
    attn_out[base]      = p0;
    attn_out[base + 8]  = p1;
    attn_out[base + 16] = p2;
    attn_out[base + 24] = p3;
  }
  // wsum partial: pos=(row&7)*8+col, chunk-pair sum via xor-32; one writer/pos.
  p0 += __shfl_xor(p0, 32, 64);
  p1 += __shfl_xor(p1, 32, 64);
  p2 += __shfl_xor(p2, 32, 64);
  p3 += __shfl_xor(p3, 32, 64);
  if (ln < 32 && (ln & 15) < 8) {
    const int rb = (ln >> 4) * 4;
    const int c8 = ln & 7;
    float* w = wsp + wid * 64;
    w[(rb + 0) * 8 + c8] = p0;
    w[(rb + 1) * 8 + c8] = p1;
    w[(rb + 2) * 8 + c8] = p2;
    w[(rb + 3) * 8 + c8] = p3;
  }
  __syncthreads();

  // ---- PV: 16 independent coalesced v loads; wsum via broadcast LDS reads
  const float4* v4 = reinterpret_cast<const float4*>(vin) + (size_t)bn * 4096;
  float4 av = make_float4(0.f, 0.f, 0.f, 0.f);
  #pragma unroll
  for (int i = 0; i < 16; ++i) {
    const int r = wid + 4 * i;
    float w = wsp[r] + wsp[64 + r] + wsp[128 + r] + wsp[192 + r];
    float4 vv = v4[r * 64 + ln];
    av.x += w * vv.x; av.y += w * vv.y; av.z += w * vv.z; av.w += w * vv.w;
  }
  float* s_red = reinterpret_cast<float*>(sm);   // [4][260] alias on dead B-frag area
  *reinterpret_cast<float4*>(&s_red[wid * 260 + (ln << 2)]) = av;
  __syncthreads();

  out[(size_t)bn * D + tid] =
      s_red[tid] + s_red[260 + tid] + s_red[520 + tid] + s_red[780 + tid];
}

}  // namespace

extern "C" void kernel_launch(void* const* d_in, const int* in_sizes, int n_in,
                              void* d_out, int out_size, void* d_ws, size_t ws_size,
                              hipStream_t stream) {
  const float* q = (const float*)d_in[0];   // (8,128,1,256)
  const float* k = (const float*)d_in[1];   // (8,128,64,256)
  const float* v = (const float*)d_in[2];   // (8,128,64,256)
  const float* W = (const float*)d_in[3];   // (8,256,256)
  const float* b = (const float*)d_in[4];   // (8,)

  float* out  = (float*)d_out;              // output: 262144 f32
  float* attn = out + 262144;               // attn:   524288 f32
  char*  ws   = (char*)d_ws;
  float* qWbuf = (float*)(ws + OFF_QW);     // 8 MiB f32 qW

  hipLaunchKernelGGL(prep_kernel,       dim3(384),  dim3(256), 0, stream, q, W, ws);
  hipLaunchKernelGGL(qw_mfma_kernel,    dim3(256),  dim3(256), 0, stream, ws, qWbuf);
  hipLaunchKernelGGL(attn_fused_kernel, dim3(1024), dim3(256), 0, stream,
                     qWbuf, k, v, b, out, attn);
}